// Round 9
// baseline (449.170 us; speedup 1.0000x reference)
//
#include <hip/hip_runtime.h>

#define LOG2E 1.44269504088896f

typedef _Float16 f16;
typedef __fp16 fp16v2 __attribute__((ext_vector_type(2)));  // cvt_pkrtz return type
typedef _Float16 f16x8 __attribute__((ext_vector_type(8)));
typedef float f32x4 __attribute__((ext_vector_type(4)));

#define NP 3
#define NN 4096
#define FF 1024
#define HH 8
#define DD 8
#define HD 64

// workspace byte offsets
#define OFF_F1S   0            // f32 [3][8][4096]      (f1 * log2e)
#define OFF_F2S   393216       // f16 [3][8][4096]      (f2 * log2e)
#define OFF_F2MAX 589824       // f32 [24]              (max_m f2s)
#define OFF_FTST  590080       // f16 [3][64][4096]     (fts transposed: [p][hd][n])
#define OFF_MULTI 2162944      // f32 [4096][3][64]     (per-path embeddings)
// k-split partial slabs (fp32 [3][4096][64] each). Slab0 aliases OFF_MULTI:
// multi is only written by kB, strictly after kAe has consumed the slabs.
#define OFF_FP0   2162944
#define SLAB_BYTES 3145728

// output float offsets
#define OUT_FINAL 65536        // 4096*16
#define OUT_ALPHA 327680       // 65536 + 4096*64

// ---------------------------------------------------------------------------
// Kernel A1: k-split partial GEMM, 64x64 tile. Grid (64, 3, 4): z = K-quarter
// (256 K per block). 4x4 per-thread tile: per k one b128(A) + one b128(B)
// feeds 16 FMA -> per-wave LDS traffic 512KB (was 768KB with the 2x4 tile);
// kA1 is LDS-pipe-bound at 12 waves/CU so this is the binding cut.
// T14 named-register staging retained.
// ---------------------------------------------------------------------------
__global__ __launch_bounds__(256) void kA1(const float* __restrict__ inp,
                                           const float* __restrict__ W,
                                           char* __restrict__ ws) {
    __shared__ float At[32 * 68];     // [k][row] transposed A tile (pad 68)
    __shared__ float Bt[32 * 64];     // [k][hd]
    const int tid = threadIdx.x;
    const int p = blockIdx.y;
    const int n0 = blockIdx.x * 64;
    const int kb0 = blockIdx.z * 8;   // 8 kb-tiles of 32 k = 256 K

    const int tr = tid >> 4, tc = tid & 15;
    const int r0 = tr * 4, c0 = tc * 4;       // 4 rows x 4 cols per thread
    const int sr = tid >> 2, sak = (tid & 3) * 8;  // A staging: row, 8 k's
    const int bk = tid >> 3, bh = tid & 7;    // B staging: k, head

    const float* aP = inp + ((size_t)p * NN + n0 + sr) * FF + kb0 * 32 + sak;
    const float* bP = W + (((size_t)p * HH + bh) * FF + kb0 * 32 + bk) * DD;
    float* bDst = &Bt[bk * 64 + bh * 8];
    float* slab = (float*)(ws + OFF_FP0 + (size_t)blockIdx.z * SLAB_BYTES);

    // T14 staging state: named registers
    float4 pa0, pa1, pb0, pb1;

#define KA_ISSUE(kb) do { \
        const float* ap_ = aP + (kb) * 32; \
        pa0 = *(const float4*)(ap_); \
        pa1 = *(const float4*)(ap_ + 4); \
        const float* bp_ = bP + (size_t)(kb) * 32 * DD; \
        pb0 = *(const float4*)(bp_); \
        pb1 = *(const float4*)(bp_ + 4); \
    } while (0)

#define KA_COMMIT() do { \
        At[(sak + 0) * 68 + sr] = pa0.x; \
        At[(sak + 1) * 68 + sr] = pa0.y; \
        At[(sak + 2) * 68 + sr] = pa0.z; \
        At[(sak + 3) * 68 + sr] = pa0.w; \
        At[(sak + 4) * 68 + sr] = pa1.x; \
        At[(sak + 5) * 68 + sr] = pa1.y; \
        At[(sak + 6) * 68 + sr] = pa1.z; \
        At[(sak + 7) * 68 + sr] = pa1.w; \
        *(float4*)(bDst) = pb0; \
        *(float4*)(bDst + 4) = pb1; \
    } while (0)

    float acc[4][4] = {};

    KA_ISSUE(0);
    KA_COMMIT();
    KA_ISSUE(1);
    __syncthreads();

    #pragma unroll 1
    for (int kb = 0; kb < 8; ++kb) {
        #pragma unroll
        for (int k = 0; k < 32; ++k) {
            float4 av = *(const float4*)&At[k * 68 + r0];
            float4 bv = *(const float4*)&Bt[k * 64 + c0];
            float aa[4] = {av.x, av.y, av.z, av.w};
            float bb4[4] = {bv.x, bv.y, bv.z, bv.w};
            #pragma unroll
            for (int i = 0; i < 4; ++i)
                #pragma unroll
                for (int j = 0; j < 4; ++j) acc[i][j] += aa[i] * bb4[j];
        }
        __syncthreads();
        if (kb < 7) {
            KA_COMMIT();                     // write tile kb+1 (regs ready)
            if (kb < 6) KA_ISSUE(kb + 2);    // in flight during next compute
            __syncthreads();
        }
    }
#undef KA_ISSUE
#undef KA_COMMIT

    // store partials (coalesced: 16 threads x float4 = 256B per row)
    #pragma unroll
    for (int i = 0; i < 4; ++i) {
        float4 o;
        o.x = acc[i][0]; o.y = acc[i][1]; o.z = acc[i][2]; o.w = acc[i][3];
        *(float4*)(slab + ((size_t)p * NN + n0 + r0 + i) * HD + c0) = o;
    }
}

// ---------------------------------------------------------------------------
// Kernel Ae: sum the four K-quarter slabs -> fts tile in LDS, then f1/f2
// epilogue and transposed fp16 ftsT copy. Grid (64, 3), bulk-coalesced.
// ---------------------------------------------------------------------------
__global__ __launch_bounds__(256) void kAe(const float* __restrict__ a1w,
                                           const float* __restrict__ a1b,
                                           const float* __restrict__ a2w,
                                           const float* __restrict__ a2b,
                                           char* __restrict__ ws) {
    __shared__ float ftile[64 * 68];  // [row][hd]
    const int tid = threadIdx.x;
    const int p = blockIdx.y;
    const int n0 = blockIdx.x * 64;

    const size_t boff = ((size_t)p * NN + n0) * HD;
    const float* s0 = (const float*)(ws + OFF_FP0 + 0 * SLAB_BYTES) + boff;
    const float* s1 = (const float*)(ws + OFF_FP0 + 1 * SLAB_BYTES) + boff;
    const float* s2 = (const float*)(ws + OFF_FP0 + 2 * SLAB_BYTES) + boff;
    const float* s3 = (const float*)(ws + OFF_FP0 + 3 * SLAB_BYTES) + boff;

    // each thread sums 16 contiguous floats (4 float4 per slab)
    {
        const int base = tid * 16;
        const int row = base >> 6, col = base & 63;
        #pragma unroll
        for (int q = 0; q < 4; ++q) {
            float4 u = *(const float4*)(s0 + base + q * 4);
            float4 v = *(const float4*)(s1 + base + q * 4);
            float4 x = *(const float4*)(s2 + base + q * 4);
            float4 y = *(const float4*)(s3 + base + q * 4);
            float4 o;
            o.x = (u.x + v.x) + (x.x + y.x);
            o.y = (u.y + v.y) + (x.y + y.y);
            o.z = (u.z + v.z) + (x.z + y.z);
            o.w = (u.w + v.w) + (x.w + y.w);
            *(float4*)&ftile[row * 68 + col + q * 4] = o;
        }
    }
    __syncthreads();

    float* f1s = (float*)(ws + OFF_F1S);
    f16* f2s = (f16*)(ws + OFF_F2S);
    // f1/f2 epilogue: 512 tasks (64 rows x 8 heads)
    #pragma unroll
    for (int rep = 0; rep < 2; ++rep) {
        int task = tid + rep * 256;
        int row = task >> 3, h = task & 7;
        const float* fb = &ftile[row * 68 + h * 8];
        float s1v = a1b[p * HH + h], s2v = a2b[p * HH + h];
        #pragma unroll
        for (int d = 0; d < 8; ++d) {
            float v = fb[d];
            s1v += v * a1w[((size_t)p * HH + h) * DD + d];
            s2v += v * a2w[((size_t)p * HH + h) * DD + d];
        }
        f1s[((size_t)p * HH + h) * NN + n0 + row] = s1v * LOG2E;
        f2s[((size_t)p * HH + h) * NN + n0 + row] = (f16)(s2v * LOG2E);
    }
    // transposed fp16 fts: ftsT[p][hd][n]
    {
        f16* ftsT = (f16*)(ws + OFF_FTST);
        int cc2 = tid >> 2, rq = (tid & 3) * 16;
        union { f16 h[16]; uint4 u[2]; } pk;
        #pragma unroll
        for (int i = 0; i < 16; ++i) pk.h[i] = (f16)ftile[(rq + i) * 68 + cc2];
        uint4* dst = (uint4*)(ftsT + ((size_t)p * HD + cc2) * NN + n0 + rq);
        dst[0] = pk.u[0];
        dst[1] = pk.u[1];
    }
}

// ---------------------------------------------------------------------------
// Kernel A2: f2smax[p][h] = max_m f2s[p][h][m]. Vectorized uint4 loads.
// ---------------------------------------------------------------------------
__global__ __launch_bounds__(64) void kA2(char* __restrict__ ws) {
    const f16* f2s = (const f16*)(ws + OFF_F2S);
    float* fmax = (float*)(ws + OFF_F2MAX);
    int b = blockIdx.x;
    int lane = threadIdx.x;
    float v = -1e30f;
    #pragma unroll
    for (int it = 0; it < 8; ++it) {
        union { uint4 u; f16 h[8]; } t;
        t.u = *(const uint4*)(f2s + (size_t)b * NN + ((size_t)it * 64 + lane) * 8);
        #pragma unroll
        for (int j = 0; j < 8; ++j) v = fmaxf(v, (float)t.h[j]);
    }
    #pragma unroll
    for (int off = 32; off >= 1; off >>= 1) v = fmaxf(v, __shfl_xor(v, off, 64));
    if (lane == 0) fmax[b] = v;
}

// ---------------------------------------------------------------------------
// Kernel B: fused attention, single-barrier double-buffered chunks (128 m).
// vs r5-r7 (two barriers per 256-chunk): commit of chunk ch+1 into the idle
// buffer happens INSIDE iteration ch (the barrier ending iter ch-1 already
// guarantees that buffer is free), so the globally-serialized commit window
// between the two barriers disappears -> one barrier per chunk, commits
// overlap other waves' compute. Denominator "ones" row replaced by register
// cndmask (r1-validated). 8 f16 converts packed into 4 cvt_pkrtz (RTZ vs
// RTN: <=1 ulp f16, inside existing quantization). Bias prefetch 2-deep.
// LDS: ftsL[2] 2x17408 + f2L[2] 2x4352 = 43520 B -> still 3 blocks/CU.
// ---------------------------------------------------------------------------
__global__ __launch_bounds__(256, 3) void kB(const float* __restrict__ bias,
                                             const float* __restrict__ h_bias,
                                             char* __restrict__ ws) {
    __shared__ __align__(16) char smem[43520];
    // ftsL buf b: smem + b*17408          ([64][136] f16)
    // f2L  buf b: smem + 34816 + b*4352   ([8][136] f32)

    const int tid = threadIdx.x;
    const int lane = tid & 63, wv = tid >> 6;
    const int c = lane & 15, kg = lane >> 4;
    const int p = blockIdx.y;
    const int n0 = blockIdx.x * 16;
    const int n = n0 + c;

    const float* f1s = (const float*)(ws + OFF_F1S);
    const f16* f2s = (const f16*)(ws + OFF_F2S);
    const float* fmax = (const float*)(ws + OFF_F2MAX);
    const f16* ftsG = (const f16*)(ws + OFF_FTST);
    float* multi = (float*)(ws + OFF_MULTI);

    // Per-head constants with -ub folded in:
    //   max(x,0.01x)-ub = max(x-ub, 0.01x-ub), x = f1+f2 (log2e-scaled)
    float A1[8], B1[8];
    #pragma unroll
    for (int h = 0; h < 8; ++h) {
        float f1v = f1s[((size_t)p * 8 + h) * NN + n];
        float fm = fmax[p * 8 + h];
        float x = f1v + fm;
        float lr = fmaxf(x, 0.01f * x);
        float ub = lr + 8.0f * LOG2E;  // bias < 8 assumed (N(0,1), max~5.95)
        A1[h] = f1v - ub;
        B1[h] = fmaf(0.01f, f1v, -ub);
    }

    // denominator column: register ones (cndmask), no LDS ones row
    union { f16x8 v; unsigned short u[8]; } onesu;
    #pragma unroll
    for (int i = 0; i < 8; ++i) onesu.u[i] = 0x3C00;  // f16 1.0
    const bool isones = (c >= 8);

    // staging indices: 16-lane group = one full 128-col row (256B coalesced)
    const int srow = tid >> 4;          // 0..15 (rows srow+16k, k=0..3)
    const int se = tid & 15;            // 16B chunk within row
    const int f2r = tid >> 5;           // 0..7
    const int f2c = (tid & 31) * 4;     // 0..124

    const f16* ftsP = ftsG + (size_t)p * HD * NN + (size_t)srow * NN + se * 8;
    const f16* f2P = f2s + (size_t)p * 8 * NN + (size_t)f2r * NN + f2c;
    const int ldo = srow * 136 + se * 8;   // f16 elements

    const int mloc = wv * 32 + kg * 8;     // wave's m-slice in chunk
    const int rowsel = (c & 7) * 136;      // (garbage row for c>=8, replaced)

    const float* bb_base = bias + ((size_t)p * NN + n) * NN + mloc;

    f32x4 acc[8] = {};

    // T14 staging state: NAMED registers
    uint4 r0, r1, r2, r3;
    uint2 rv;

#define ISSUE(ch) do { \
        const f16* gs_ = ftsP + (ch) * 128; \
        r0 = *(const uint4*)(gs_); \
        r1 = *(const uint4*)(gs_ + (size_t)16 * NN); \
        r2 = *(const uint4*)(gs_ + (size_t)32 * NN); \
        r3 = *(const uint4*)(gs_ + (size_t)48 * NN); \
        rv = *(const uint2*)(f2P + (ch) * 128); \
    } while (0)

#define COMMIT(buf) do { \
        f16* fb_ = (f16*)(smem + (buf) * 17408) + ldo; \
        *(uint4*)(fb_) = r0; \
        *(uint4*)(fb_ + 16 * 136) = r1; \
        *(uint4*)(fb_ + 32 * 136) = r2; \
        *(uint4*)(fb_ + 48 * 136) = r3; \
        union { uint2 u; f16 h[4]; } t_; \
        t_.u = rv; \
        float4 fv_; \
        fv_.x = (float)t_.h[0]; fv_.y = (float)t_.h[1]; \
        fv_.z = (float)t_.h[2]; fv_.w = (float)t_.h[3]; \
        *(float4*)((float*)(smem + 34816 + (buf) * 4352) + f2r * 136 + f2c) = fv_; \
    } while (0)

    // prologue: stage chunk 0 -> buf0, issue chunk 1, bias for chunks 0/1
    ISSUE(0);
    COMMIT(0);
    ISSUE(1);
    float4 uA0 = *(const float4*)(bb_base);
    float4 uA1 = *(const float4*)(bb_base + 4);
    float4 vA0 = *(const float4*)(bb_base + 128);
    float4 vA1 = *(const float4*)(bb_base + 132);
    __syncthreads();

    #pragma unroll 1
    for (int ch = 0; ch < 32; ++ch) {
        const int cur = ch & 1;
        // commit chunk ch+1 into the idle buffer (free since barrier ch-1);
        // overlaps other waves' compute on buf[cur]
        if (ch < 31) COMMIT(cur ^ 1);
        if (ch < 30) ISSUE(ch + 2);
        // bias prefetch 2 chunks ahead (clamped; re-read cached)
        const int chn = (ch + 2 < 32) ? ch + 2 : 31;
        const float* bpn = bb_base + chn * 128;
        float4 wA0 = *(const float4*)(bpn);
        float4 wA1 = *(const float4*)(bpn + 4);

        const f16* fts_ = (const f16*)(smem + cur * 17408);
        const float* f2_ = (const float*)(smem + 34816 + cur * 4352);

        float bbl[8] = {uA0.x * LOG2E, uA0.y * LOG2E, uA0.z * LOG2E, uA0.w * LOG2E,
                        uA1.x * LOG2E, uA1.y * LOG2E, uA1.z * LOG2E, uA1.w * LOG2E};
        #pragma unroll
        for (int h = 0; h < 8; ++h) {
            const float* f2p = f2_ + h * 136 + mloc;
            float4 f2a = *(const float4*)f2p;
            float4 f2b = *(const float4*)(f2p + 4);
            float f2arr[8] = {f2a.x, f2a.y, f2a.z, f2a.w, f2b.x, f2b.y, f2b.z, f2b.w};
            f16x8 bf = *(const f16x8*)(fts_ + rowsel + h * 8 * 136 + mloc);
            if (isones) bf = onesu.v;
            union { f16x8 v; fp16v2 p2[4]; } af;
            #pragma unroll
            for (int jj = 0; jj < 4; ++jj) {
                float x0 = f2arr[2 * jj], x1 = f2arr[2 * jj + 1];
                float e0 = __builtin_amdgcn_exp2f(
                    fmaxf(x0 + A1[h], fmaf(0.01f, x0, B1[h])) + bbl[2 * jj]);
                float e1 = __builtin_amdgcn_exp2f(
                    fmaxf(x1 + A1[h], fmaf(0.01f, x1, B1[h])) + bbl[2 * jj + 1]);
                af.p2[jj] = __builtin_amdgcn_cvt_pkrtz(e0, e1);
            }
            acc[h] = __builtin_amdgcn_mfma_f32_16x16x32_f16(af.v, bf, acc[h], 0, 0, 0);
        }
        __syncthreads();
        uA0 = vA0; uA1 = vA1; vA0 = wA0; vA1 = wA1;
    }
#undef ISSUE
#undef COMMIT

    // epilogue: cross-wave reduction of D-frags (+denominator col 8) via LDS
    float* red = (float*)smem;  // [4][8][16][9] = 18432 B
    #pragma unroll
    for (int h = 0; h < 8; ++h) {
        if (c <= 8) {
            #pragma unroll
            for (int r = 0; r < 4; ++r)
                red[((wv * 8 + h) * 16 + kg * 4 + r) * 9 + c] = acc[h][r];
        }
    }
    __syncthreads();
    #pragma unroll
    for (int rep = 0; rep < 4; ++rep) {
        int idx = tid + rep * 256;
        int R = idx >> 6, hd = idx & 63;
        int h = hd >> 3, d = hd & 7;
        float v = 0.f, l = 0.f;
        #pragma unroll
        for (int w = 0; w < 4; ++w) {
            v += red[((w * 8 + h) * 16 + R) * 9 + d];
            l += red[((w * 8 + h) * 16 + R) * 9 + 8];
        }
        float o = v / l + h_bias[(p * 8 + h) * 8 + d];
        o = o > 0.f ? o : (__builtin_amdgcn_exp2f(o * LOG2E) - 1.0f);  // elu
        multi[((size_t)(n0 + R) * NP + p) * HD + hd] = o;
    }
}

// ---------------------------------------------------------------------------
// Kernel C: semantic attention + classifier. 16 nodes per block. FROZEN.
// ---------------------------------------------------------------------------
__global__ __launch_bounds__(256) void kC(const float* __restrict__ Ws,
                                          const float* __restrict__ bsv,
                                          const float* __restrict__ uv,
                                          const float* __restrict__ Wc,
                                          const float* __restrict__ bcv,
                                          char* __restrict__ ws,
                                          float* __restrict__ out) {
    __shared__ float WsL[64 * 128];
    __shared__ float mult[16 * 3 * 64];
    __shared__ float WcL[64 * 16];
    __shared__ float uL[128], bsL[128], bcL[16];
    __shared__ float vred[16 * 3 * 16];
    __shared__ float alphaL[16 * 3];
    __shared__ float fin[16 * 64];
    const int tid = threadIdx.x;
    const int n0 = blockIdx.x * 16;
    const float* multi = (const float*)(ws + OFF_MULTI);

    for (int i = tid; i < 64 * 128; i += 256) WsL[i] = Ws[i];
    for (int i = tid; i < 3072; i += 256) mult[i] = multi[(size_t)n0 * 192 + i];
    for (int i = tid; i < 1024; i += 256) WcL[i] = Wc[i];
    if (tid < 128) { uL[tid] = uv[tid]; bsL[tid] = bsv[tid]; }
    if (tid < 16) bcL[tid] = bcv[tid];
    __syncthreads();

    const int nl = tid >> 4, j = tid & 15;
    for (int p = 0; p < 3; ++p) {
        float va[8] = {};
        for (int e = 0; e < 64; ++e) {
            float me = mult[(nl * 3 + p) * 64 + e];
            #pragma unroll
            for (int i = 0; i < 8; ++i) va[i] += me * WsL[e * 128 + j + 16 * i];
        }
        float part = 0.f;
        #pragma unroll
        for (int i = 0; i < 8; ++i) part += tanhf(va[i] + bsL[j + 16 * i]) * uL[j + 16 * i];
        vred[(nl * 3 + p) * 16 + j] = part;
    }
    __syncthreads();
    if (tid < 16) {
        float sc[3];
        for (int p = 0; p < 3; ++p) {
            float s = 0.f;
            for (int jj = 0; jj < 16; ++jj) s += vred[(tid * 3 + p) * 16 + jj];
            sc[p] = s;
        }
        float mx = fmaxf(sc[0], fmaxf(sc[1], sc[2]));
        float e0 = __builtin_amdgcn_exp2f((sc[0] - mx) * LOG2E);
        float e1 = __builtin_amdgcn_exp2f((sc[1] - mx) * LOG2E);
        float e2 = __builtin_amdgcn_exp2f((sc[2] - mx) * LOG2E);
        float inv = 1.f / (e0 + e1 + e2);
        float a0 = e0 * inv, a1 = e1 * inv, a2 = e2 * inv;
        alphaL[tid * 3 + 0] = a0; alphaL[tid * 3 + 1] = a1; alphaL[tid * 3 + 2] = a2;
        out[OUT_ALPHA + (size_t)(n0 + tid) * 3 + 0] = a0;
        out[OUT_ALPHA + (size_t)(n0 + tid) * 3 + 1] = a1;
        out[OUT_ALPHA + (size_t)(n0 + tid) * 3 + 2] = a2;
    }
    __syncthreads();
    for (int idx = tid; idx < 1024; idx += 256) {
        int nn2 = idx >> 6, e = idx & 63;
        float f = 0.f;
        for (int p = 0; p < 3; ++p) f += mult[(nn2 * 3 + p) * 64 + e] * alphaL[nn2 * 3 + p];
        fin[nn2 * 64 + e] = f;
        out[OUT_FINAL + (size_t)(n0 + nn2) * 64 + e] = f;
    }
    __syncthreads();
    {
        int nn2 = tid >> 4, cc2 = tid & 15;
        float lg = bcL[cc2];
        for (int e = 0; e < 64; ++e) lg += fin[nn2 * 64 + e] * WcL[e * 16 + cc2];
        out[(size_t)(n0 + nn2) * 16 + cc2] = lg;
    }
}

extern "C" void kernel_launch(void* const* d_in, const int* in_sizes, int n_in,
                              void* d_out, int out_size, void* d_ws, size_t ws_size,
                              hipStream_t stream) {
    (void)in_sizes; (void)n_in; (void)out_size; (void)ws_size;
    const float* inp = (const float*)d_in[0];
    const float* bias = (const float*)d_in[1];
    const float* W = (const float*)d_in[2];
    const float* a1w = (const float*)d_in[3];
    const float* a1b = (const float*)d_in[4];
    const float* a2w = (const float*)d_in[5];
    const float* a2b = (const float*)d_in[6];
    const float* hb = (const float*)d_in[7];
    const float* Wsv = (const float*)d_in[8];
    const float* bsv = (const float*)d_in[9];
    const float* uv = (const float*)d_in[10];
    const float* Wcv = (const float*)d_in[11];
    const float* bcv = (const float*)d_in[12];
    char* ws = (char*)d_ws;
    float* out = (float*)d_out;

    hipLaunchKernelGGL(kA1, dim3(64, 3, 4), dim3(256), 0, stream, inp, W, ws);
    hipLaunchKernelGGL(kAe, dim3(64, 3), dim3(256), 0, stream, a1w, a1b, a2w, a2b, ws);
    hipLaunchKernelGGL(kA2, dim3(24), dim3(64), 0, stream, ws);
    hipLaunchKernelGGL(kB, dim3(256, 3), dim3(256), 0, stream, bias, hb, ws);
    hipLaunchKernelGGL(kC, dim3(256), dim3(256), 0, stream, Wsv, bsv, uv, Wcv, bcv, ws, out);
}

// Round 10
// 400.375 us; speedup vs baseline: 1.1219x; 1.1219x over previous
//
#include <hip/hip_runtime.h>

#define LOG2E 1.44269504088896f

typedef _Float16 f16;
typedef __fp16 fp16v2 __attribute__((ext_vector_type(2)));  // cvt_pkrtz return type
typedef _Float16 f16x8 __attribute__((ext_vector_type(8)));
typedef float f32x4 __attribute__((ext_vector_type(4)));

#define NP 3
#define NN 4096
#define FF 1024
#define HH 8
#define DD 8
#define HD 64

// workspace byte offsets
#define OFF_F1S   0            // f32 [3][8][4096]      (f1 * log2e)
#define OFF_F2S   393216       // f16 [3][8][4096]      (f2 * log2e)
#define OFF_F2MAX 589824       // f32 [24]              (max_m f2s)
#define OFF_FTST  590080       // f16 [3][64][4096]     (fts transposed: [p][hd][n])
#define OFF_MULTI 2162944      // f32 [4096][3][64]     (per-path embeddings)
// k-split partial slabs (fp32 [3][4096][64] each). Slab0 aliases OFF_MULTI:
// multi is only written by kB, strictly after kAe has consumed the slabs.
#define OFF_FP0   2162944
#define SLAB_BYTES 3145728

// output float offsets
#define OUT_FINAL 65536        // 4096*16
#define OUT_ALPHA 327680       // 65536 + 4096*64

// ---------------------------------------------------------------------------
// Kernel A1: k-split partial GEMM, 64x64 tile. Grid (64, 3, 4): z = K-quarter
// (256 K per block). 4x4 per-thread tile; T14 named-register staging.
// ---------------------------------------------------------------------------
__global__ __launch_bounds__(256) void kA1(const float* __restrict__ inp,
                                           const float* __restrict__ W,
                                           char* __restrict__ ws) {
    __shared__ float At[32 * 68];     // [k][row] transposed A tile (pad 68)
    __shared__ float Bt[32 * 64];     // [k][hd]
    const int tid = threadIdx.x;
    const int p = blockIdx.y;
    const int n0 = blockIdx.x * 64;
    const int kb0 = blockIdx.z * 8;   // 8 kb-tiles of 32 k = 256 K

    const int tr = tid >> 4, tc = tid & 15;
    const int r0 = tr * 4, c0 = tc * 4;       // 4 rows x 4 cols per thread
    const int sr = tid >> 2, sak = (tid & 3) * 8;  // A staging: row, 8 k's
    const int bk = tid >> 3, bh = tid & 7;    // B staging: k, head

    const float* aP = inp + ((size_t)p * NN + n0 + sr) * FF + kb0 * 32 + sak;
    const float* bP = W + (((size_t)p * HH + bh) * FF + kb0 * 32 + bk) * DD;
    float* bDst = &Bt[bk * 64 + bh * 8];
    float* slab = (float*)(ws + OFF_FP0 + (size_t)blockIdx.z * SLAB_BYTES);

    // T14 staging state: named registers
    float4 pa0, pa1, pb0, pb1;

#define KA_ISSUE(kb) do { \
        const float* ap_ = aP + (kb) * 32; \
        pa0 = *(const float4*)(ap_); \
        pa1 = *(const float4*)(ap_ + 4); \
        const float* bp_ = bP + (size_t)(kb) * 32 * DD; \
        pb0 = *(const float4*)(bp_); \
        pb1 = *(const float4*)(bp_ + 4); \
    } while (0)

#define KA_COMMIT() do { \
        At[(sak + 0) * 68 + sr] = pa0.x; \
        At[(sak + 1) * 68 + sr] = pa0.y; \
        At[(sak + 2) * 68 + sr] = pa0.z; \
        At[(sak + 3) * 68 + sr] = pa0.w; \
        At[(sak + 4) * 68 + sr] = pa1.x; \
        At[(sak + 5) * 68 + sr] = pa1.y; \
        At[(sak + 6) * 68 + sr] = pa1.z; \
        At[(sak + 7) * 68 + sr] = pa1.w; \
        *(float4*)(bDst) = pb0; \
        *(float4*)(bDst + 4) = pb1; \
    } while (0)

    float acc[4][4] = {};

    KA_ISSUE(0);
    KA_COMMIT();
    KA_ISSUE(1);
    __syncthreads();

    #pragma unroll 1
    for (int kb = 0; kb < 8; ++kb) {
        #pragma unroll
        for (int k = 0; k < 32; ++k) {
            float4 av = *(const float4*)&At[k * 68 + r0];
            float4 bv = *(const float4*)&Bt[k * 64 + c0];
            float aa[4] = {av.x, av.y, av.z, av.w};
            float bb4[4] = {bv.x, bv.y, bv.z, bv.w};
            #pragma unroll
            for (int i = 0; i < 4; ++i)
                #pragma unroll
                for (int j = 0; j < 4; ++j) acc[i][j] += aa[i] * bb4[j];
        }
        __syncthreads();
        if (kb < 7) {
            KA_COMMIT();                     // write tile kb+1 (regs ready)
            if (kb < 6) KA_ISSUE(kb + 2);    // in flight during next compute
            __syncthreads();
        }
    }
#undef KA_ISSUE
#undef KA_COMMIT

    // store partials (coalesced: 16 threads x float4 = 256B per row)
    #pragma unroll
    for (int i = 0; i < 4; ++i) {
        float4 o;
        o.x = acc[i][0]; o.y = acc[i][1]; o.z = acc[i][2]; o.w = acc[i][3];
        *(float4*)(slab + ((size_t)p * NN + n0 + r0 + i) * HD + c0) = o;
    }
}

// ---------------------------------------------------------------------------
// Kernel Ae: sum the four K-quarter slabs -> fts tile in LDS, then f1/f2
// epilogue and transposed fp16 ftsT copy. Grid (64, 3), bulk-coalesced.
// ---------------------------------------------------------------------------
__global__ __launch_bounds__(256) void kAe(const float* __restrict__ a1w,
                                           const float* __restrict__ a1b,
                                           const float* __restrict__ a2w,
                                           const float* __restrict__ a2b,
                                           char* __restrict__ ws) {
    __shared__ float ftile[64 * 68];  // [row][hd]
    const int tid = threadIdx.x;
    const int p = blockIdx.y;
    const int n0 = blockIdx.x * 64;

    const size_t boff = ((size_t)p * NN + n0) * HD;
    const float* s0 = (const float*)(ws + OFF_FP0 + 0 * SLAB_BYTES) + boff;
    const float* s1 = (const float*)(ws + OFF_FP0 + 1 * SLAB_BYTES) + boff;
    const float* s2 = (const float*)(ws + OFF_FP0 + 2 * SLAB_BYTES) + boff;
    const float* s3 = (const float*)(ws + OFF_FP0 + 3 * SLAB_BYTES) + boff;

    // each thread sums 16 contiguous floats (4 float4 per slab)
    {
        const int base = tid * 16;
        const int row = base >> 6, col = base & 63;
        #pragma unroll
        for (int q = 0; q < 4; ++q) {
            float4 u = *(const float4*)(s0 + base + q * 4);
            float4 v = *(const float4*)(s1 + base + q * 4);
            float4 x = *(const float4*)(s2 + base + q * 4);
            float4 y = *(const float4*)(s3 + base + q * 4);
            float4 o;
            o.x = (u.x + v.x) + (x.x + y.x);
            o.y = (u.y + v.y) + (x.y + y.y);
            o.z = (u.z + v.z) + (x.z + y.z);
            o.w = (u.w + v.w) + (x.w + y.w);
            *(float4*)&ftile[row * 68 + col + q * 4] = o;
        }
    }
    __syncthreads();

    float* f1s = (float*)(ws + OFF_F1S);
    f16* f2s = (f16*)(ws + OFF_F2S);
    // f1/f2 epilogue: 512 tasks (64 rows x 8 heads)
    #pragma unroll
    for (int rep = 0; rep < 2; ++rep) {
        int task = tid + rep * 256;
        int row = task >> 3, h = task & 7;
        const float* fb = &ftile[row * 68 + h * 8];
        float s1v = a1b[p * HH + h], s2v = a2b[p * HH + h];
        #pragma unroll
        for (int d = 0; d < 8; ++d) {
            float v = fb[d];
            s1v += v * a1w[((size_t)p * HH + h) * DD + d];
            s2v += v * a2w[((size_t)p * HH + h) * DD + d];
        }
        f1s[((size_t)p * HH + h) * NN + n0 + row] = s1v * LOG2E;
        f2s[((size_t)p * HH + h) * NN + n0 + row] = (f16)(s2v * LOG2E);
    }
    // transposed fp16 fts: ftsT[p][hd][n]
    {
        f16* ftsT = (f16*)(ws + OFF_FTST);
        int cc2 = tid >> 2, rq = (tid & 3) * 16;
        union { f16 h[16]; uint4 u[2]; } pk;
        #pragma unroll
        for (int i = 0; i < 16; ++i) pk.h[i] = (f16)ftile[(rq + i) * 68 + cc2];
        uint4* dst = (uint4*)(ftsT + ((size_t)p * HD + cc2) * NN + n0 + rq);
        dst[0] = pk.u[0];
        dst[1] = pk.u[1];
    }
}

// ---------------------------------------------------------------------------
// Kernel A2: f2smax[p][h] = max_m f2s[p][h][m]. Vectorized uint4 loads.
// ---------------------------------------------------------------------------
__global__ __launch_bounds__(64) void kA2(char* __restrict__ ws) {
    const f16* f2s = (const f16*)(ws + OFF_F2S);
    float* fmax = (float*)(ws + OFF_F2MAX);
    int b = blockIdx.x;
    int lane = threadIdx.x;
    float v = -1e30f;
    #pragma unroll
    for (int it = 0; it < 8; ++it) {
        union { uint4 u; f16 h[8]; } t;
        t.u = *(const uint4*)(f2s + (size_t)b * NN + ((size_t)it * 64 + lane) * 8);
        #pragma unroll
        for (int j = 0; j < 8; ++j) v = fmaxf(v, (float)t.h[j]);
    }
    #pragma unroll
    for (int off = 32; off >= 1; off >>= 1) v = fmaxf(v, __shfl_xor(v, off, 64));
    if (lane == 0) fmax[b] = v;
}

// ---------------------------------------------------------------------------
// Kernel B: fused attention — REVERTED to the proven r6/r7 two-barrier
// 256-m-chunk T14 structure (r9's single-barrier 128-chunk variant regressed
// 124->157us: head-of-iteration commit forced a vmcnt drain every barrier
// with only ~600cy of load cover). Only retained r9 change: cvt_pkrtz packs
// the 8 f16 converts into 4 (pure VALU saving, schedule untouched).
// ---------------------------------------------------------------------------
__global__ __launch_bounds__(256, 3) void kB(const float* __restrict__ bias,
                                             const float* __restrict__ h_bias,
                                             char* __restrict__ ws) {
    __shared__ __align__(16) char smem[42768];
    f16* ftsL = (f16*)smem;               // [65][264] f16, row 64 = ones
    float* f2L = (float*)(smem + 34320);  // [8][264] f32

    const int tid = threadIdx.x;
    const int lane = tid & 63, wv = tid >> 6;
    const int c = lane & 15, kg = lane >> 4;
    const int p = blockIdx.y;
    const int n0 = blockIdx.x * 16;
    const int n = n0 + c;

    const float* f1s = (const float*)(ws + OFF_F1S);
    const f16* f2s = (const f16*)(ws + OFF_F2S);
    const float* fmax = (const float*)(ws + OFF_F2MAX);
    const f16* ftsG = (const f16*)(ws + OFF_FTST);
    float* multi = (float*)(ws + OFF_MULTI);

    // Per-head constants with -ub folded in:
    //   max(x,0.01x)-ub = max(x-ub, 0.01x-ub), x = f1+f2 (log2e-scaled)
    float A1[8], B1[8];
    #pragma unroll
    for (int h = 0; h < 8; ++h) {
        float f1v = f1s[((size_t)p * 8 + h) * NN + n];
        float fm = fmax[p * 8 + h];
        float x = f1v + fm;
        float lr = fmaxf(x, 0.01f * x);
        float ub = lr + 8.0f * LOG2E;  // bias < 8 assumed (N(0,1), max~5.95)
        A1[h] = f1v - ub;
        B1[h] = fmaf(0.01f, f1v, -ub);
    }

    // ones row for the denominator column
    for (int i = tid; i < 264; i += 256) ftsL[64 * 264 + i] = (f16)1.0f;

    // staging indices: 8-lane group sg covers a contiguous 128B row segment
    const int sg = tid >> 3, se = tid & 7;        // group, element-in-group
    const int srow = sg & 7, sq = sg >> 3;        // base row, column quarter
    const int f2r = tid >> 5, f2c = (tid & 31) * 8;  // f2 staging

    const f16* ftsP = ftsG + (size_t)p * HD * NN + sq * 64 + se * 8;
    const f16* f2P = f2s + (size_t)p * 8 * NN + (size_t)f2r * NN + f2c;
    f16* ldst = ftsL + srow * 264 + sq * 64 + se * 8;

    // per-h LDS row select for the MFMA B operand (row 64 = ones for c>=8)
    const int rowsel = (c < 8) ? c * 264 : 64 * 264;
    const int hstep = (c < 8) ? 8 * 264 : 0;

    const float* bb_base = bias + ((size_t)p * NN + n) * NN + wv * 64 + kg * 8;

    f32x4 acc[8] = {};

    // T14 staging state: NAMED registers (never an indexed array)
    uint4 r0, r1, r2, r3, r4, r5, r6, r7, rv;

#define ISSUE(ch) do { \
        const f16* gs_ = ftsP + (ch) * 256; \
        r0 = *(const uint4*)(gs_ + (size_t)(srow +  0) * NN); \
        r1 = *(const uint4*)(gs_ + (size_t)(srow +  8) * NN); \
        r2 = *(const uint4*)(gs_ + (size_t)(srow + 16) * NN); \
        r3 = *(const uint4*)(gs_ + (size_t)(srow + 24) * NN); \
        r4 = *(const uint4*)(gs_ + (size_t)(srow + 32) * NN); \
        r5 = *(const uint4*)(gs_ + (size_t)(srow + 40) * NN); \
        r6 = *(const uint4*)(gs_ + (size_t)(srow + 48) * NN); \
        r7 = *(const uint4*)(gs_ + (size_t)(srow + 56) * NN); \
        rv = *(const uint4*)(f2P + (ch) * 256); \
    } while (0)

#define COMMIT() do { \
        *(uint4*)(ldst + 0 * 8 * 264) = r0; \
        *(uint4*)(ldst + 1 * 8 * 264) = r1; \
        *(uint4*)(ldst + 2 * 8 * 264) = r2; \
        *(uint4*)(ldst + 3 * 8 * 264) = r3; \
        *(uint4*)(ldst + 4 * 8 * 264) = r4; \
        *(uint4*)(ldst + 5 * 8 * 264) = r5; \
        *(uint4*)(ldst + 6 * 8 * 264) = r6; \
        *(uint4*)(ldst + 7 * 8 * 264) = r7; \
        union { uint4 u; f16 h[8]; } t16_; \
        t16_.u = rv; \
        float4 lo_, hi_; \
        lo_.x = (float)t16_.h[0]; lo_.y = (float)t16_.h[1]; \
        lo_.z = (float)t16_.h[2]; lo_.w = (float)t16_.h[3]; \
        hi_.x = (float)t16_.h[4]; hi_.y = (float)t16_.h[5]; \
        hi_.z = (float)t16_.h[6]; hi_.w = (float)t16_.h[7]; \
        *(float4*)(f2L + f2r * 264 + f2c) = lo_; \
        *(float4*)(f2L + f2r * 264 + f2c + 4) = hi_; \
    } while (0)

    // prologue: stage chunk 0, issue chunk 1, load bias chunk 0
    ISSUE(0);
    COMMIT();
    ISSUE(1);
    float4 uA0 = *(const float4*)(bb_base);
    float4 uA1 = *(const float4*)(bb_base + 4);
    float4 uB0 = *(const float4*)(bb_base + 32);
    float4 uB1 = *(const float4*)(bb_base + 36);
    __syncthreads();

    #pragma unroll 1
    for (int ch = 0; ch < 16; ++ch) {
        // prefetch bias for next chunk (clamped; last iter re-reads, cached)
        const int chn = (ch + 1 < 16) ? ch + 1 : 15;
        const float* bpn = bb_base + chn * 256;
        float4 nA0 = *(const float4*)(bpn);
        float4 nA1 = *(const float4*)(bpn + 4);
        float4 nB0 = *(const float4*)(bpn + 32);
        float4 nB1 = *(const float4*)(bpn + 36);

        #pragma unroll
        for (int s = 0; s < 2; ++s) {
            const int mloc = wv * 64 + s * 32 + kg * 8;
            float4 bv0 = s ? uB0 : uA0;
            float4 bv1 = s ? uB1 : uA1;
            float bbl[8] = {bv0.x * LOG2E, bv0.y * LOG2E, bv0.z * LOG2E, bv0.w * LOG2E,
                            bv1.x * LOG2E, bv1.y * LOG2E, bv1.z * LOG2E, bv1.w * LOG2E};
            #pragma unroll
            for (int h = 0; h < 8; ++h) {
                const float* f2p = f2L + h * 264 + mloc;
                float4 f2a = *(const float4*)f2p;
                float4 f2b = *(const float4*)(f2p + 4);
                float f2arr[8] = {f2a.x, f2a.y, f2a.z, f2a.w, f2b.x, f2b.y, f2b.z, f2b.w};
                f16x8 bf = *(const f16x8*)(ftsL + rowsel + h * hstep + mloc);
                union { f16x8 v; fp16v2 p2[4]; } af;
                #pragma unroll
                for (int jj = 0; jj < 4; ++jj) {
                    float x0 = f2arr[2 * jj], x1 = f2arr[2 * jj + 1];
                    float e0 = __builtin_amdgcn_exp2f(
                        fmaxf(x0 + A1[h], fmaf(0.01f, x0, B1[h])) + bbl[2 * jj]);
                    float e1 = __builtin_amdgcn_exp2f(
                        fmaxf(x1 + A1[h], fmaf(0.01f, x1, B1[h])) + bbl[2 * jj + 1]);
                    af.p2[jj] = __builtin_amdgcn_cvt_pkrtz(e0, e1);
                }
                acc[h] = __builtin_amdgcn_mfma_f32_16x16x32_f16(af.v, bf, acc[h], 0, 0, 0);
            }
        }
        __syncthreads();   // all waves done reading LDS for chunk ch
        if (ch < 15) {
            COMMIT();                      // write chunk ch+1 (regs ready)
            if (ch < 14) ISSUE(ch + 2);    // in flight during next compute
            __syncthreads();               // chunk ch+1 visible
        }
        uA0 = nA0; uA1 = nA1; uB0 = nB0; uB1 = nB1;
    }
#undef ISSUE
#undef COMMIT

    // epilogue: cross-wave reduction of D-frags (+denominator col 8) via LDS
    float* red = (float*)smem;  // [4][8][16][9]
    #pragma unroll
    for (int h = 0; h < 8; ++h) {
        if (c <= 8) {
            #pragma unroll
            for (int r = 0; r < 4; ++r)
                red[((wv * 8 + h) * 16 + kg * 4 + r) * 9 + c] = acc[h][r];
        }
    }
    __syncthreads();
    #pragma unroll
    for (int rep = 0; rep < 4; ++rep) {
        int idx = tid + rep * 256;
        int R = idx >> 6, hd = idx & 63;
        int h = hd >> 3, d = hd & 7;
        float v = 0.f, l = 0.f;
        #pragma unroll
        for (int w = 0; w < 4; ++w) {
            v += red[((w * 8 + h) * 16 + R) * 9 + d];
            l += red[((w * 8 + h) * 16 + R) * 9 + 8];
        }
        float o = v / l + h_bias[(p * 8 + h) * 8 + d];
        o = o > 0.f ? o : (__builtin_amdgcn_exp2f(o * LOG2E) - 1.0f);  // elu
        multi[((size_t)(n0 + R) * NP + p) * HD + hd] = o;
    }
}

// ---------------------------------------------------------------------------
// Kernel C: semantic attention + classifier. 16 nodes per block. FROZEN.
// ---------------------------------------------------------------------------
__global__ __launch_bounds__(256) void kC(const float* __restrict__ Ws,
                                          const float* __restrict__ bsv,
                                          const float* __restrict__ uv,
                                          const float* __restrict__ Wc,
                                          const float* __restrict__ bcv,
                                          char* __restrict__ ws,
                                          float* __restrict__ out) {
    __shared__ float WsL[64 * 128];
    __shared__ float mult[16 * 3 * 64];
    __shared__ float WcL[64 * 16];
    __shared__ float uL[128], bsL[128], bcL[16];
    __shared__ float vred[16 * 3 * 16];
    __shared__ float alphaL[16 * 3];
    __shared__ float fin[16 * 64];
    const int tid = threadIdx.x;
    const int n0 = blockIdx.x * 16;
    const float* multi = (const float*)(ws + OFF_MULTI);

    for (int i = tid; i < 64 * 128; i += 256) WsL[i] = Ws[i];
    for (int i = tid; i < 3072; i += 256) mult[i] = multi[(size_t)n0 * 192 + i];
    for (int i = tid; i < 1024; i += 256) WcL[i] = Wc[i];
    if (tid < 128) { uL[tid] = uv[tid]; bsL[tid] = bsv[tid]; }
    if (tid < 16) bcL[tid] = bcv[tid];
    __syncthreads();

    const int nl = tid >> 4, j = tid & 15;
    for (int p = 0; p < 3; ++p) {
        float va[8] = {};
        for (int e = 0; e < 64; ++e) {
            float me = mult[(nl * 3 + p) * 64 + e];
            #pragma unroll
            for (int i = 0; i < 8; ++i) va[i] += me * WsL[e * 128 + j + 16 * i];
        }
        float part = 0.f;
        #pragma unroll
        for (int i = 0; i < 8; ++i) part += tanhf(va[i] + bsL[j + 16 * i]) * uL[j + 16 * i];
        vred[(nl * 3 + p) * 16 + j] = part;
    }
    __syncthreads();
    if (tid < 16) {
        float sc[3];
        for (int p = 0; p < 3; ++p) {
            float s = 0.f;
            for (int jj = 0; jj < 16; ++jj) s += vred[(tid * 3 + p) * 16 + jj];
            sc[p] = s;
        }
        float mx = fmaxf(sc[0], fmaxf(sc[1], sc[2]));
        float e0 = __builtin_amdgcn_exp2f((sc[0] - mx) * LOG2E);
        float e1 = __builtin_amdgcn_exp2f((sc[1] - mx) * LOG2E);
        float e2 = __builtin_amdgcn_exp2f((sc[2] - mx) * LOG2E);
        float inv = 1.f / (e0 + e1 + e2);
        float a0 = e0 * inv, a1 = e1 * inv, a2 = e2 * inv;
        alphaL[tid * 3 + 0] = a0; alphaL[tid * 3 + 1] = a1; alphaL[tid * 3 + 2] = a2;
        out[OUT_ALPHA + (size_t)(n0 + tid) * 3 + 0] = a0;
        out[OUT_ALPHA + (size_t)(n0 + tid) * 3 + 1] = a1;
        out[OUT_ALPHA + (size_t)(n0 + tid) * 3 + 2] = a2;
    }
    __syncthreads();
    for (int idx = tid; idx < 1024; idx += 256) {
        int nn2 = idx >> 6, e = idx & 63;
        float f = 0.f;
        for (int p = 0; p < 3; ++p) f += mult[(nn2 * 3 + p) * 64 + e] * alphaL[nn2 * 3 + p];
        fin[nn2 * 64 + e] = f;
        out[OUT_FINAL + (size_t)(n0 + nn2) * 64 + e] = f;
    }
    __syncthreads();
    {
        int nn2 = tid >> 4, cc2 = tid & 15;
        float lg = bcL[cc2];
        for (int e = 0; e < 64; ++e) lg += fin[nn2 * 64 + e] * WcL[e * 16 + cc2];
        out[(size_t)(n0 + nn2) * 16 + cc2] = lg;
    }
}

extern "C" void kernel_launch(void* const* d_in, const int* in_sizes, int n_in,
                              void* d_out, int out_size, void* d_ws, size_t ws_size,
                              hipStream_t stream) {
    (void)in_sizes; (void)n_in; (void)out_size; (void)ws_size;
    const float* inp = (const float*)d_in[0];
    const float* bias = (const float*)d_in[1];
    const float* W = (const float*)d_in[2];
    const float* a1w = (const float*)d_in[3];
    const float* a1b = (const float*)d_in[4];
    const float* a2w = (const float*)d_in[5];
    const float* a2b = (const float*)d_in[6];
    const float* hb = (const float*)d_in[7];
    const float* Wsv = (const float*)d_in[8];
    const float* bsv = (const float*)d_in[9];
    const float* uv = (const float*)d_in[10];
    const float* Wcv = (const float*)d_in[11];
    const float* bcv = (const float*)d_in[12];
    char* ws = (char*)d_ws;
    float* out = (float*)d_out;

    hipLaunchKernelGGL(kA1, dim3(64, 3, 4), dim3(256), 0, stream, inp, W, ws);
    hipLaunchKernelGGL(kAe, dim3(64, 3), dim3(256), 0, stream, a1w, a1b, a2w, a2b, ws);
    hipLaunchKernelGGL(kA2, dim3(24), dim3(64), 0, stream, ws);
    hipLaunchKernelGGL(kB, dim3(256, 3), dim3(256), 0, stream, bias, hb, ws);
    hipLaunchKernelGGL(kC, dim3(256), dim3(256), 0, stream, Wsv, bsv, uv, Wcv, bcv, ws, out);
}